// Round 4
// baseline (209.115 us; speedup 1.0000x reference)
//
#include <hip/hip_runtime.h>
#include <stdint.h>

typedef unsigned long long ull;

#define NA 8400
#define NB 32
#define KTOP 300
#define NC 80
#define CH 9           // 1024*9 = 9216 >= 8400
#define NKPAD 9216
#define NCOPY 16       // histogram copies (one per wave)
#define HSTRIDE 257    // copies of one bucket land in different banks

// out layout: boxes_yxyx @0 ; in_zone @38400 ; scores @48000 ; classes @57600 ;
//             centers_yx @67200 ; keep @86400 ; total 96000 floats
#define O1 38400
#define O2 48000
#define O3 57600
#define O4 67200
#define O5 86400

// ws layout: keys @0 (32*8400*4 B); per-batch region @ 2 MiB + b*16384:
//   sel (300 ull) @ +0 ; mask (1500 ull) @ +2400 B
#define WS_BATCH_BASE (2u << 20)
#define WS_BATCH_STRIDE 16384

// ---------------- A: per-anchor score key (memory-bound, unchanged) ----------------
__global__ __launch_bounds__(256) void score_kernel(const float* __restrict__ pred,
                                                    uint32_t* __restrict__ keys) {
    __shared__ float sP[128 * 85];
    const int blk = blockIdx.x;                       // 2100 blocks * 128 anchors
    const float4* g4 = (const float4*)(pred + (size_t)blk * 128 * 85);
    float4* l4 = (float4*)sP;
    for (int i = threadIdx.x; i < (128 * 85 / 4); i += 256) l4[i] = g4[i];
    __syncthreads();
    const int t = threadIdx.x;
    if (t < 128) {
        const float* p = sP + t * 85;
        float obj = p[4];
        float b0 = p[5], b1 = p[6], b2 = p[7], b3 = p[8];
        #pragma unroll
        for (int c = 4; c < NC; c += 4) {
            b0 = fmaxf(b0, p[5 + c]);
            b1 = fmaxf(b1, p[6 + c]);
            b2 = fmaxf(b2, p[7 + c]);
            b3 = fmaxf(b3, p[8 + c]);
        }
        float best = fmaxf(fmaxf(b0, b1), fmaxf(b2, b3));
        float sc = obj * best;
        uint32_t u = (sc >= 0.2f) ? (__float_as_uint(sc) | 0x80000000u) : 0x007FFFFFu;
        keys[(size_t)blk * 128 + t] = u;
    }
}

// ---------------- B: per-batch radix select + rank sort -> ws.sel ----------------
__global__ __launch_bounds__(1024) void select_kernel(const uint32_t* __restrict__ keys,
                                                      uint8_t* __restrict__ ws) {
    __shared__ uint32_t sKeys[NKPAD];
    __shared__ ull sSel[KTOP];
    __shared__ ull sSorted[KTOP];
    __shared__ uint32_t sH[NCOPY * HSTRIDE];
    __shared__ uint32_t sWTot[16];
    __shared__ uint32_t sBc[2];
    __shared__ uint32_t sRank[KTOP];

    const int b = blockIdx.x;
    const int t = threadIdx.x;
    const int lane = t & 63;
    const int wv = t >> 6;

    {   // coalesced key load (batch base 16B-aligned: 33600 % 16 == 0)
        const uint4* g4 = (const uint4*)(keys + (size_t)b * NA);
        uint4* l4 = (uint4*)sKeys;
        for (int i = t; i < NA / 4; i += 1024) l4[i] = g4[i];
        for (int i = NA + t; i < NKPAD; i += 1024) sKeys[i] = 0u;  // pads never selectable
    }
    if (t < KTOP) sRank[t] = 0u;
    __syncthreads();

    const int beg = t * CH;                    // contiguous chunk: lanes 32 apart share a
                                               // bank at different addrs -> 2-way (free)
    // ---- radix select: exact 300th-largest key ----
    uint32_t prefix = 0, r = KTOP;
    for (int round = 0; round < 4; ++round) {
        const int shift = 24 - 8 * round;
        for (int i = t; i < NCOPY * HSTRIDE; i += 1024) sH[i] = 0u;
        __syncthreads();
        const uint32_t pmask = (round == 0) ? 0u : (0xFFFFFFFFu << (shift + 8));
        const uint32_t pref = prefix & pmask;
        uint32_t* hw = &sH[wv * HSTRIDE];
        #pragma unroll
        for (int e = 0; e < CH; ++e) {
            uint32_t k = sKeys[beg + e];
            if ((k & pmask) == pref)
                atomicAdd(&hw[(k >> shift) & 0xFFu], 1u);
        }
        __syncthreads();
        if (wv == 0) {                  // single-wave 256-bin suffix scan + pick
            uint32_t v0 = 0, v1 = 0, v2 = 0, v3 = 0;
            #pragma unroll
            for (int c = 0; c < NCOPY; ++c) {
                const uint32_t* hc = &sH[c * HSTRIDE];
                v0 += hc[lane]; v1 += hc[64 + lane];
                v2 += hc[128 + lane]; v3 += hc[192 + lane];
            }
            uint32_t s0 = v0, s1 = v1, s2 = v2, s3 = v3;
            #pragma unroll
            for (int off = 1; off < 64; off <<= 1) {
                uint32_t o0 = __shfl_down(s0, off, 64), o1 = __shfl_down(s1, off, 64);
                uint32_t o2 = __shfl_down(s2, off, 64), o3 = __shfl_down(s3, off, 64);
                if (lane + off < 64) { s0 += o0; s1 += o1; s2 += o2; s3 += o3; }
            }
            uint32_t T1 = __shfl(s1, 0, 64), T2 = __shfl(s2, 0, 64), T3 = __shfl(s3, 0, 64);
            uint32_t S0 = s0 + T1 + T2 + T3;
            uint32_t S1 = s1 + T2 + T3;
            uint32_t S2 = s2 + T3;
            uint32_t S3 = s3;
            if (S0 >= r && S0 - v0 < r) { sBc[0] = prefix | ((uint32_t)lane << shift);         sBc[1] = r - (S0 - v0); }
            if (S1 >= r && S1 - v1 < r) { sBc[0] = prefix | ((uint32_t)(64  + lane) << shift); sBc[1] = r - (S1 - v1); }
            if (S2 >= r && S2 - v2 < r) { sBc[0] = prefix | ((uint32_t)(128 + lane) << shift); sBc[1] = r - (S2 - v2); }
            if (S3 >= r && S3 - v3 < r) { sBc[0] = prefix | ((uint32_t)(192 + lane) << shift); sBc[1] = r - (S3 - v3); }
        }
        __syncthreads();
        prefix = sBc[0]; r = sBc[1];
        // sBc rewritten only after >=2 barriers next round. safe.
    }
    const uint32_t kth = prefix;
    const uint32_t rem = r;
    const uint32_t cntgt = KTOP - rem;

    // ---- compaction via packed (gt,eq) prefix scan: no atomics, deterministic ----
    {
        uint32_t gtc = 0, eqc = 0;
        #pragma unroll
        for (int e = 0; e < CH; ++e) {
            uint32_t k = sKeys[beg + e];
            gtc += (k > kth) ? 1u : 0u;
            eqc += (k == kth) ? 1u : 0u;
        }
        uint32_t pack = (gtc << 16) | eqc;      // totals: gt<=300, eq<=8400 -> no overflow
        uint32_t ps = pack;
        #pragma unroll
        for (int off = 1; off < 64; off <<= 1) {
            uint32_t o = __shfl_up(ps, off, 64);
            if (lane >= off) ps += o;
        }
        if (lane == 63) sWTot[wv] = ps;
        __syncthreads();
        uint32_t excl = ps - pack;              // exclusive within wave
        #pragma unroll
        for (int w2 = 0; w2 < 16; ++w2) if (w2 < wv) excl += sWTot[w2];
        uint32_t gtoff = excl >> 16;
        uint32_t eqoff = excl & 0xFFFFu;
        #pragma unroll
        for (int e = 0; e < CH; ++e) {
            uint32_t k = sKeys[beg + e];
            uint32_t idx = (uint32_t)(beg + e);
            if (k > kth) {
                sSel[gtoff++] = ((ull)k << 32) | (ull)(0xFFFFFFFFu - idx);
            } else if (k == kth) {
                if (eqoff < rem)                 // ascending anchor order == top_k tie-break
                    sSel[cntgt + eqoff] = ((ull)k << 32) | (ull)(0xFFFFFFFFu - idx);
                eqoff++;
            }
        }
        __syncthreads();
    }

    // ---- rank sort over 1200 work items (unique 64-bit keys -> rank is a permutation) ----
    for (int p2 = t; p2 < KTOP * 4; p2 += 1024) {
        const int i = p2 >> 2;
        const int q = p2 & 3;
        const ull my = sSel[i];
        const int j0 = q * 75, j1 = j0 + 75;
        uint32_t cnt = 0;
        for (int j = j0; j < j1; ++j)
            cnt += (sSel[j] > my) ? 1u : 0u;
        if (cnt) atomicAdd(&sRank[i], cnt);
    }
    __syncthreads();
    if (t < KTOP) sSorted[sRank[t]] = sSel[t];
    __syncthreads();

    ull* selW = (ull*)(ws + WS_BATCH_BASE + (size_t)b * WS_BATCH_STRIDE);
    if (t < KTOP) selW[t] = sSorted[t];
}

// ---------------- C: grid (2, NB). x=0: gather+argmax+outputs. x=1: IoU masks ----------------
__global__ __launch_bounds__(1024) void prep_kernel(const float* __restrict__ pred,
                                                    uint8_t* __restrict__ ws,
                                                    float* __restrict__ out) {
    #pragma clang fp contract(off)
    __shared__ float sB0[KTOP], sB1[KTOP], sB2[KTOP], sB3[KTOP];
    const int b = blockIdx.y;
    const int t = threadIdx.x;
    const ull* sel = (const ull*)(ws + WS_BATCH_BASE + (size_t)b * WS_BATCH_STRIDE);
    const size_t bo = (size_t)b * KTOP;

    if (blockIdx.x == 0) {
        // ---- gather: 2 threads/row, 4 first-max streams each, exact first-max ----
        if (t < 2 * KTOP) {
            const int row = t >> 1;
            const int half = t & 1;
            const uint32_t a = 0xFFFFFFFFu - (uint32_t)sel[row];
            const float* p = pred + ((size_t)b * NA + a) * 85;
            const int cbase = half * 40;
            float v0 = p[5 + cbase], v1 = p[6 + cbase], v2 = p[7 + cbase], v3 = p[8 + cbase];
            int   c0 = cbase, c1 = cbase + 1, c2 = cbase + 2, c3 = cbase + 3;
            #pragma unroll
            for (int c = 4; c < 40; c += 4) {
                float w0 = p[5 + cbase + c],     w1 = p[6 + cbase + c];
                float w2 = p[7 + cbase + c],     w3 = p[8 + cbase + c];
                if (w0 > v0) { v0 = w0; c0 = cbase + c; }        // strict >: first-in-stream
                if (w1 > v1) { v1 = w1; c1 = cbase + c + 1; }
                if (w2 > v2) { v2 = w2; c2 = cbase + c + 2; }
                if (w3 > v3) { v3 = w3; c3 = cbase + c + 3; }
            }
            float bv = v0; int bc = c0;
            if (v1 > bv || (v1 == bv && c1 < bc)) { bv = v1; bc = c1; }
            if (v2 > bv || (v2 == bv && c2 < bc)) { bv = v2; bc = c2; }
            if (v3 > bv || (v3 == bv && c3 < bc)) { bv = v3; bc = c3; }
            float pv = __shfl_xor(bv, 1, 64);    // pairs (2k,2k+1) never straddle a wave
            int   pc = __shfl_xor(bc, 1, 64);
            if (half == 0) {
                if (pv > bv) { bv = pv; bc = pc; }   // partner indices larger: tie keeps ours
                float x = p[0], y = p[1], w = p[2], h = p[3], obj = p[4];
                float hw = w * 0.5f, hh = h * 0.5f;
                float x1 = x - hw, y1 = y - hh, x2 = x + hw, y2 = y + hh;
                out[(bo + row) * 4 + 0] = y1;
                out[(bo + row) * 4 + 1] = x1;
                out[(bo + row) * 4 + 2] = y2;
                out[(bo + row) * 4 + 3] = x2;
                out[O4 + (bo + row) * 2 + 0] = (y1 + y2) * 0.5f;
                out[O4 + (bo + row) * 2 + 1] = (x1 + x2) * 0.5f;
                out[O2 + bo + row] = fmaxf(obj, bv);
                out[O3 + bo + row] = (float)bc;
            }
        }
    } else {
        // ---- boxes -> LDS (recomputed; bit-identical ops) ----
        if (t < KTOP) {
            const uint32_t a = 0xFFFFFFFFu - (uint32_t)sel[t];
            const float* p = pred + ((size_t)b * NA + a) * 85;   // 340B rows: no float4
            float x = p[0], y = p[1], w = p[2], h = p[3];
            float hw = w * 0.5f, hh = h * 0.5f;
            sB0[t] = x - hw; sB1[t] = y - hh; sB2[t] = x + hw; sB3[t] = y + hh;
        }
        __syncthreads();
        // ---- IoU masks, role-major, uniform-j loop (broadcast LDS reads) ----
        ull* maskW = (ull*)(ws + WS_BATCH_BASE + (size_t)b * WS_BATCH_STRIDE + 2400);
        for (int p2 = t; p2 < KTOP * 5; p2 += 1024) {
            const int role = p2 / KTOP;
            const int i = p2 - role * KTOP;
            const int j0 = role * 64;
            int jmax = j0 + 64; if (jmax > KTOP) jmax = KTOP;
            float x1 = sB0[i], y1 = sB1[i], x2 = sB2[i], y2 = sB3[i];
            float ai = fmaxf(x2 - x1, 0.0f) * fmaxf(y2 - y1, 0.0f);
            ull bits = 0ull;
            for (int j = j0; j < jmax; ++j) {
                float bx1 = sB0[j], by1 = sB1[j], bx2 = sB2[j], by2 = sB3[j];
                float aj = fmaxf(bx2 - bx1, 0.0f) * fmaxf(by2 - by1, 0.0f);
                float iw = fminf(x2, bx2) - fmaxf(x1, bx1); iw = fmaxf(iw, 0.0f);
                float ih = fminf(y2, by2) - fmaxf(y1, by1); ih = fmaxf(ih, 0.0f);
                float inter = iw * ih;
                float den = ai + aj;         // mirror reference op order exactly
                den = den - inter;
                den = den + 1e-9f;
                float iou = inter / den;
                if (j > i && iou > 0.45f) bits |= (1ull << (j - j0));
            }
            maskW[i * 5 + role] = bits;
        }
    }
}

// ---------------- D: NMS (wave 0) overlapped with zone parity (waves 1-5) ----------------
__global__ __launch_bounds__(512) void finish_kernel(const float* __restrict__ zone,
                                                     const uint8_t* __restrict__ ws,
                                                     float* __restrict__ out) {
    #pragma clang fp contract(off)
    __shared__ ull sMask[KTOP * 5];
    __shared__ ull sSel[KTOP];
    __shared__ uint32_t sPar[KTOP];
    __shared__ ull sKeepF[5];
    __shared__ float sZone[16];
    const int b = blockIdx.x;
    const int t = threadIdx.x;
    const int lane = t & 63;
    const int wv = t >> 6;
    const ull* selG = (const ull*)(ws + WS_BATCH_BASE + (size_t)b * WS_BATCH_STRIDE);
    const ull* maskG = selG + KTOP;          // +2400 B
    for (int i = t; i < KTOP; i += 512) sSel[i] = selG[i];
    for (int i = t; i < KTOP * 5; i += 512) sMask[i] = maskG[i];
    if (t < 16) sZone[t] = zone[t];
    __syncthreads();

    const size_t bo = (size_t)b * KTOP;
    if (wv == 0) {
        ull rm[5][5];
        ull kw[5];
        #pragma unroll
        for (int w = 0; w < 5; ++w) {
            int i = w * 64 + lane;
            bool f = (i < KTOP) && (((uint32_t)(sSel[i] >> 32)) > 0x007FFFFFu);
            kw[w] = __ballot(f);             // keep-init, replicated in every lane
            #pragma unroll
            for (int ww = 0; ww < 5; ++ww)
                rm[w][ww] = (i < KTOP) ? sMask[i * 5 + ww] : 0ull;
        }
        #pragma unroll
        for (int w = 0; w < 5; ++w) {
            ull cur = kw[w];
            while (cur) {
                int ib = __builtin_ctzll(cur);          // accepted box i = w*64+ib
                ull m0 = __shfl(rm[w][0], ib);
                ull m1 = __shfl(rm[w][1], ib);
                ull m2 = __shfl(rm[w][2], ib);
                ull m3 = __shfl(rm[w][3], ib);
                ull m4 = __shfl(rm[w][4], ib);
                kw[0] &= ~m0; kw[1] &= ~m1; kw[2] &= ~m2; kw[3] &= ~m3; kw[4] &= ~m4;
                ull done = (ib == 63) ? 0ull : (~0ull << (ib + 1));
                cur = kw[w] & done;
            }
        }
        if (lane == 0) {
            #pragma unroll
            for (int w = 0; w < 5; ++w) sKeepF[w] = kw[w];
        }
    } else if (t >= 64 && t < 64 + KTOP) {
        const int i = t - 64;
        float cy = out[O4 + (bo + i) * 2 + 0];   // exact stored center
        float cx = out[O4 + (bo + i) * 2 + 1];
        int cnt = 0;
        #pragma unroll
        for (int e = 0; e < 8; ++e) {
            float xi = sZone[2 * e], yi = sZone[2 * e + 1];
            int ep = (e + 7) & 7;               // zr = roll(zone, 1)
            float xj = sZone[2 * ep], yj = sZone[2 * ep + 1];
            bool gyi = yi > cy, gyj = yj > cy;
            if (gyi != gyj) {
                float gx = (xj - xi) * (cy - yi) / (yj - yi) + xi;
                if (gx > cx) cnt++;
            }
        }
        sPar[i] = (uint32_t)(cnt & 1);
    }
    __syncthreads();

    if (t < KTOP) {
        int kp = (int)((sKeepF[t >> 6] >> (t & 63)) & 1ull);
        int inz = (sPar[t] && kp) ? 1 : 0;
        out[O1 + bo + t] = (float)inz;
        out[O5 + bo + t] = (float)kp;
    }
}

extern "C" void kernel_launch(void* const* d_in, const int* in_sizes, int n_in,
                              void* d_out, int out_size, void* d_ws, size_t ws_size,
                              hipStream_t stream) {
    const float* pred = (const float*)d_in[0];   // (32,8400,85) fp32
    const float* zone = (const float*)d_in[1];   // (8,2) fp32
    float* out = (float*)d_out;                  // 96000 fp32
    uint32_t* keys = (uint32_t*)d_ws;            // keys @0 ; per-batch sel/mask @2MiB
    uint8_t* ws = (uint8_t*)d_ws;

    score_kernel<<<(NB * NA) / 128, 256, 0, stream>>>(pred, keys);
    select_kernel<<<NB, 1024, 0, stream>>>(keys, ws);
    prep_kernel<<<dim3(2, NB), 1024, 0, stream>>>(pred, ws, out);
    finish_kernel<<<NB, 512, 0, stream>>>(zone, ws, out);
}

// Round 5
// 197.534 us; speedup vs baseline: 1.0586x; 1.0586x over previous
//
#include <hip/hip_runtime.h>
#include <stdint.h>

typedef unsigned long long ull;

#define NA 8400
#define NB 32
#define KTOP 300
#define NC 80
#define CH 9           // 1024*9 = 9216 >= 8400
#define NKPAD 9216
#define NBIN 616       // dense bins over key range [0xBE4CCCCD, 0xBF800000) >> 15, +1 for below-range
#define HSTR 617       // odd stride: copies of one bin staggered across banks
#define NCPY 8         // histogram copies (one per 128 threads)
#define BASEK 0xBE4CCCCDu   // bits of 0.2f with sign-flag set (keys are score-bits | 0x80000000)
#define CANDMAX 256

// out layout: boxes_yxyx @0 ; in_zone @38400 ; scores @48000 ; classes @57600 ;
//             centers_yx @67200 ; keep @86400 ; total 96000 floats
#define O1 38400
#define O2 48000
#define O3 57600
#define O4 67200
#define O5 86400

// ws: keys @0 (32*8400*4 B). per-batch region @ 2 MiB + b*8192:
//   sel (300 ull) @+0 ; boxes planes x1,y1,x2,y2 (4*300 f32) @+2400 B
#define WS_BATCH_BASE (2u << 20)
#define WS_BATCH_STRIDE 8192

// ---------------- A: per-anchor score key (memory-bound, unchanged) ----------------
__global__ __launch_bounds__(256) void score_kernel(const float* __restrict__ pred,
                                                    uint32_t* __restrict__ keys) {
    __shared__ float sP[128 * 85];
    const int blk = blockIdx.x;                       // 2100 blocks * 128 anchors
    const float4* g4 = (const float4*)(pred + (size_t)blk * 128 * 85);
    float4* l4 = (float4*)sP;
    for (int i = threadIdx.x; i < (128 * 85 / 4); i += 256) l4[i] = g4[i];
    __syncthreads();
    const int t = threadIdx.x;
    if (t < 128) {
        const float* p = sP + t * 85;
        float obj = p[4];
        float b0 = p[5], b1 = p[6], b2 = p[7], b3 = p[8];
        #pragma unroll
        for (int c = 4; c < NC; c += 4) {
            b0 = fmaxf(b0, p[5 + c]);
            b1 = fmaxf(b1, p[6 + c]);
            b2 = fmaxf(b2, p[7 + c]);
            b3 = fmaxf(b3, p[8 + c]);
        }
        float best = fmaxf(fmaxf(b0, b1), fmaxf(b2, b3));
        float sc = obj * best;
        uint32_t u = (sc >= 0.2f) ? (__float_as_uint(sc) | 0x80000000u) : 0x007FFFFFu;
        keys[(size_t)blk * 128 + t] = u;
    }
}

__device__ __forceinline__ uint32_t key_bin(uint32_t k) {
    return (k < BASEK) ? 0u : (1u + ((k - BASEK) >> 15));   // max 615 < NBIN
}

// ---------------- B: dense-histogram select + rank sort + gather/outputs ----------------
__global__ __launch_bounds__(1024) void select_kernel(const float* __restrict__ pred,
                                                      const uint32_t* __restrict__ keys,
                                                      uint8_t* __restrict__ ws,
                                                      float* __restrict__ out) {
    #pragma clang fp contract(off)
    __shared__ uint32_t sKeys[NKPAD];
    __shared__ uint32_t sH[NCPY * HSTR];
    __shared__ ull sSel[KTOP];
    __shared__ ull sSorted[KTOP];
    __shared__ ull sCand[CANDMAX];
    __shared__ uint32_t sWTot[16];
    __shared__ uint32_t sBc[2];
    __shared__ uint32_t sRank[KTOP];
    __shared__ uint32_t sCN;

    const int b = blockIdx.x;
    const int t = threadIdx.x;
    const int lane = t & 63;
    const int wv = t >> 6;

    {   // coalesced key load (batch base 16B-aligned: 33600 % 16 == 0)
        const uint4* g4 = (const uint4*)(keys + (size_t)b * NA);
        uint4* l4 = (uint4*)sKeys;
        for (int i = t; i < NA / 4; i += 1024) l4[i] = g4[i];
        for (int i = NA + t; i < NKPAD; i += 1024) sKeys[i] = 0u;  // pads -> bin 0, never selected
    }
    for (int i = t; i < NCPY * HSTR; i += 1024) sH[i] = 0u;
    if (t < KTOP) sRank[t] = 0u;
    __syncthreads();

    const int beg = t * CH;
    {   // ---- one-shot dense histogram (8 copies; ~14 keys/bin -> light conflicts) ----
        uint32_t* hw = &sH[(t >> 7) * HSTR];
        #pragma unroll
        for (int e = 0; e < CH; ++e) {
            uint32_t k = sKeys[beg + e];
            atomicAdd(&hw[key_bin(k)], 1u);
        }
    }
    __syncthreads();

    // ---- suffix scan over 616 bins (waves 0..9), find threshold bin ----
    uint32_t v = 0, s = 0;
    if (t < 640) {
        if (t < NBIN) {
            #pragma unroll
            for (int c = 0; c < NCPY; ++c) v += sH[c * HSTR + t];
        }
        s = v;
        #pragma unroll
        for (int off = 1; off < 64; off <<= 1) {
            uint32_t o = __shfl_down(s, off, 64);
            if (lane + off < 64) s += o;
        }
        if (lane == 0) sWTot[wv] = s;
    }
    __syncthreads();
    if (t < 640) {
        uint32_t S = s;
        for (int w2 = wv + 1; w2 < 10; ++w2) S += sWTot[w2];
        uint32_t above = S - v;              // count of keys in bins strictly above t
        if (above < KTOP && S >= KTOP) {     // unique crossing (requires v>0)
            sBc[0] = (uint32_t)t;
            sBc[1] = KTOP - above;
        }
    }
    __syncthreads();
    const uint32_t Tbin = sBc[0];
    const uint32_t rem = sBc[1];             // how many to take from bin Tbin
    const uint32_t cntgt = KTOP - rem;

    // ---- compact: bins>T -> sSel (unordered); bin==T -> candidates ----
    {
        uint32_t gtc = 0, eqc = 0;
        #pragma unroll
        for (int e = 0; e < CH; ++e) {
            uint32_t bin = key_bin(sKeys[beg + e]);
            gtc += (bin > Tbin) ? 1u : 0u;
            eqc += (bin == Tbin) ? 1u : 0u;
        }
        uint32_t pack = (gtc << 16) | eqc;   // gt total <= 300, eq total <= 8400: no overflow
        uint32_t ps = pack;
        #pragma unroll
        for (int off = 1; off < 64; off <<= 1) {
            uint32_t o = __shfl_up(ps, off, 64);
            if (lane >= off) ps += o;
        }
        if (lane == 63) sWTot[wv] = ps;
        __syncthreads();
        uint32_t excl = ps - pack;           // exclusive within wave
        #pragma unroll
        for (int w2 = 0; w2 < 16; ++w2) if (w2 < wv) excl += sWTot[w2];
        uint32_t gtoff = excl >> 16;
        uint32_t eqoff = excl & 0xFFFFu;
        if (t == 1023) {
            uint32_t tot = eqoff + eqc;
            sCN = (tot > CANDMAX) ? CANDMAX : tot;
        }
        #pragma unroll
        for (int e = 0; e < CH; ++e) {
            uint32_t k = sKeys[beg + e];
            uint32_t bin = key_bin(k);
            uint32_t idx = (uint32_t)(beg + e);
            if (bin > Tbin) {
                sSel[gtoff++] = ((ull)k << 32) | (ull)(0xFFFFFFFFu - idx);
            } else if (bin == Tbin) {
                if (eqoff < CANDMAX)
                    sCand[eqoff] = ((ull)k << 32) | (ull)(0xFFFFFFFFu - idx);
                eqoff++;
            }
        }
        __syncthreads();
    }

    // ---- candidate mini-rank: exact (key desc, idx asc) order; take top rem ----
    {
        int cn = (int)sCN;                   // expected ~15
        if (t < cn) {
            ull my = sCand[t];
            uint32_t rk = 0;
            for (int j = 0; j < cn; ++j) rk += (sCand[j] > my) ? 1u : 0u;
            if (rk < rem) sSel[cntgt + rk] = my;
        }
        __syncthreads();
    }

    // ---- rank sort over 1200 work items (unique 64-bit keys -> rank is a permutation) ----
    for (int p2 = t; p2 < KTOP * 4; p2 += 1024) {
        const int i = p2 >> 2;
        const int q = p2 & 3;
        const ull my = sSel[i];
        const int j0 = q * 75, j1 = j0 + 75;
        uint32_t cnt = 0;
        for (int j = j0; j < j1; ++j)
            cnt += (sSel[j] > my) ? 1u : 0u;
        if (cnt) atomicAdd(&sRank[i], cnt);
    }
    __syncthreads();
    if (t < KTOP) sSorted[sRank[t]] = sSel[t];
    __syncthreads();

    // ---- fused gather: 2 threads/row, 4 first-max streams, exact first-max ----
    ull* selW = (ull*)(ws + WS_BATCH_BASE + (size_t)b * WS_BATCH_STRIDE);
    float* boxW = (float*)(selW + KTOP);
    const size_t bo = (size_t)b * KTOP;
    if (t < KTOP) selW[t] = sSorted[t];
    if (t < 2 * KTOP) {
        const int row = t >> 1;
        const int half = t & 1;
        const uint32_t a = 0xFFFFFFFFu - (uint32_t)sSorted[row];
        const float* p = pred + ((size_t)b * NA + a) * 85;
        const int cbase = half * 40;
        float v0 = p[5 + cbase], v1 = p[6 + cbase], v2 = p[7 + cbase], v3 = p[8 + cbase];
        int   c0 = cbase, c1 = cbase + 1, c2 = cbase + 2, c3 = cbase + 3;
        #pragma unroll
        for (int c = 4; c < 40; c += 4) {
            float w0 = p[5 + cbase + c],     w1 = p[6 + cbase + c];
            float w2 = p[7 + cbase + c],     w3 = p[8 + cbase + c];
            if (w0 > v0) { v0 = w0; c0 = cbase + c; }        // strict >: first-in-stream
            if (w1 > v1) { v1 = w1; c1 = cbase + c + 1; }
            if (w2 > v2) { v2 = w2; c2 = cbase + c + 2; }
            if (w3 > v3) { v3 = w3; c3 = cbase + c + 3; }
        }
        float bv = v0; int bc = c0;
        if (v1 > bv || (v1 == bv && c1 < bc)) { bv = v1; bc = c1; }
        if (v2 > bv || (v2 == bv && c2 < bc)) { bv = v2; bc = c2; }
        if (v3 > bv || (v3 == bv && c3 < bc)) { bv = v3; bc = c3; }
        float pv = __shfl_xor(bv, 1, 64);    // pairs (2k,2k+1) never straddle a wave
        int   pc = __shfl_xor(bc, 1, 64);
        if (half == 0) {
            if (pv > bv) { bv = pv; bc = pc; }   // partner indices larger: tie keeps ours
            float x = p[0], y = p[1], w = p[2], h = p[3], obj = p[4];
            float hw = w * 0.5f, hh = h * 0.5f;
            float x1 = x - hw, y1 = y - hh, x2 = x + hw, y2 = y + hh;
            boxW[row] = x1; boxW[KTOP + row] = y1;
            boxW[2 * KTOP + row] = x2; boxW[3 * KTOP + row] = y2;
            out[(bo + row) * 4 + 0] = y1;
            out[(bo + row) * 4 + 1] = x1;
            out[(bo + row) * 4 + 2] = y2;
            out[(bo + row) * 4 + 3] = x2;
            out[O4 + (bo + row) * 2 + 0] = (y1 + y2) * 0.5f;
            out[O4 + (bo + row) * 2 + 1] = (x1 + x2) * 0.5f;
            out[O2 + bo + row] = fmaxf(obj, bv);
            out[O3 + bo + row] = (float)bc;
        }
    }
}

// ---------------- C: IoU masks (zero-skip) + NMS + zone parity + final writes ----------------
__global__ __launch_bounds__(1024) void nms_kernel(const float* __restrict__ zone,
                                                   const uint8_t* __restrict__ ws,
                                                   float* __restrict__ out) {
    #pragma clang fp contract(off)
    __shared__ float sB0[KTOP], sB1[KTOP], sB2[KTOP], sB3[KTOP];
    __shared__ ull sMask[KTOP * 5];
    __shared__ ull sSel[KTOP];
    __shared__ uint32_t sPar[KTOP];
    __shared__ ull sKeepF[5];
    __shared__ float sZone[16];
    const int b = blockIdx.x;
    const int t = threadIdx.x;
    const int lane = t & 63;
    const int wv = t >> 6;
    const ull* selG = (const ull*)(ws + WS_BATCH_BASE + (size_t)b * WS_BATCH_STRIDE);
    const float* boxG = (const float*)(selG + KTOP);
    if (t < KTOP) {
        sSel[t] = selG[t];
        sB0[t] = boxG[t];            sB1[t] = boxG[KTOP + t];
        sB2[t] = boxG[2 * KTOP + t]; sB3[t] = boxG[3 * KTOP + t];
    }
    if (t < 16) sZone[t] = zone[t];
    __syncthreads();

    // ---- IoU masks, role-major; skip role blocks entirely below the diagonal ----
    for (int p2 = t; p2 < KTOP * 5; p2 += 1024) {
        const int role = p2 / KTOP;
        const int i = p2 - role * KTOP;
        const int j0 = role * 64;
        int jmax = j0 + 64; if (jmax > KTOP) jmax = KTOP;
        if (jmax <= i + 1) { sMask[i * 5 + role] = 0ull; continue; }   // all j <= i: zero word
        float x1 = sB0[i], y1 = sB1[i], x2 = sB2[i], y2 = sB3[i];
        float ai = fmaxf(x2 - x1, 0.0f) * fmaxf(y2 - y1, 0.0f);
        ull bits = 0ull;
        for (int j = j0; j < jmax; ++j) {
            float bx1 = sB0[j], by1 = sB1[j], bx2 = sB2[j], by2 = sB3[j];
            float aj = fmaxf(bx2 - bx1, 0.0f) * fmaxf(by2 - by1, 0.0f);
            float iw = fminf(x2, bx2) - fmaxf(x1, bx1); iw = fmaxf(iw, 0.0f);
            float ih = fminf(y2, by2) - fmaxf(y1, by1); ih = fmaxf(ih, 0.0f);
            float inter = iw * ih;
            float den = ai + aj;             // mirror reference op order exactly
            den = den - inter;
            den = den + 1e-9f;
            float iou = inter / den;
            if (j > i && iou > 0.45f) bits |= (1ull << (j - j0));
        }
        sMask[i * 5 + role] = bits;
    }
    __syncthreads();

    // ---- wave 0: greedy NMS.  waves 8-12 (independent): zone parity ----
    const size_t bo = (size_t)b * KTOP;
    if (wv == 0) {
        ull rm[5][5];
        ull kw[5];
        #pragma unroll
        for (int w = 0; w < 5; ++w) {
            int i = w * 64 + lane;
            bool f = (i < KTOP) && (((uint32_t)(sSel[i] >> 32)) > 0x007FFFFFu);
            kw[w] = __ballot(f);             // keep-init, replicated in every lane
            #pragma unroll
            for (int ww = 0; ww < 5; ++ww)
                rm[w][ww] = (i < KTOP) ? sMask[i * 5 + ww] : 0ull;
        }
        #pragma unroll
        for (int w = 0; w < 5; ++w) {
            ull cur = kw[w];
            while (cur) {
                int ib = __builtin_ctzll(cur);          // accepted box i = w*64+ib
                ull m0 = __shfl(rm[w][0], ib);
                ull m1 = __shfl(rm[w][1], ib);
                ull m2 = __shfl(rm[w][2], ib);
                ull m3 = __shfl(rm[w][3], ib);
                ull m4 = __shfl(rm[w][4], ib);
                kw[0] &= ~m0; kw[1] &= ~m1; kw[2] &= ~m2; kw[3] &= ~m3; kw[4] &= ~m4;
                ull done = (ib == 63) ? 0ull : (~0ull << (ib + 1));
                cur = kw[w] & done;
            }
        }
        if (lane == 0) {
            #pragma unroll
            for (int w = 0; w < 5; ++w) sKeepF[w] = kw[w];
        }
    } else if (t >= 512 && t < 512 + KTOP) {
        const int i = t - 512;
        float cy = (sB1[i] + sB3[i]) * 0.5f;   // bit-identical to stored centers
        float cx = (sB0[i] + sB2[i]) * 0.5f;
        int cnt = 0;
        #pragma unroll
        for (int e = 0; e < 8; ++e) {
            float xi = sZone[2 * e], yi = sZone[2 * e + 1];
            int ep = (e + 7) & 7;               // zr = roll(zone, 1)
            float xj = sZone[2 * ep], yj = sZone[2 * ep + 1];
            bool gyi = yi > cy, gyj = yj > cy;
            if (gyi != gyj) {
                float gx = (xj - xi) * (cy - yi) / (yj - yi) + xi;
                if (gx > cx) cnt++;
            }
        }
        sPar[i] = (uint32_t)(cnt & 1);
    }
    __syncthreads();

    if (t < KTOP) {
        int kp = (int)((sKeepF[t >> 6] >> (t & 63)) & 1ull);
        int inz = (sPar[t] && kp) ? 1 : 0;
        out[O1 + bo + t] = (float)inz;
        out[O5 + bo + t] = (float)kp;
    }
}

extern "C" void kernel_launch(void* const* d_in, const int* in_sizes, int n_in,
                              void* d_out, int out_size, void* d_ws, size_t ws_size,
                              hipStream_t stream) {
    const float* pred = (const float*)d_in[0];   // (32,8400,85) fp32
    const float* zone = (const float*)d_in[1];   // (8,2) fp32
    float* out = (float*)d_out;                  // 96000 fp32
    uint32_t* keys = (uint32_t*)d_ws;            // keys @0 ; per-batch sel/boxes @2MiB
    uint8_t* ws = (uint8_t*)d_ws;

    score_kernel<<<(NB * NA) / 128, 256, 0, stream>>>(pred, keys);
    select_kernel<<<NB, 1024, 0, stream>>>(pred, keys, ws, out);
    nms_kernel<<<NB, 1024, 0, stream>>>(zone, ws, out);
}

// Round 6
// 193.559 us; speedup vs baseline: 1.0804x; 1.0205x over previous
//
#include <hip/hip_runtime.h>
#include <stdint.h>

typedef unsigned long long ull;

#define NA 8400
#define NB 32
#define KTOP 300
#define NC 80
#define TB 512         // per-batch kernel block size: 8 waves, VGPR budget 256 (no spills)
#define CH 17          // 512*17 = 8704 >= 8400
#define NKPAD 8704
#define NBIN 309       // 1 underflow bin + (0xBF800000-0xBE4CCCCD)>>16 = 307 -> bins 1..308
#define HSTR 311       // odd stride: copies of one bin staggered across banks
#define NCPY 8         // histogram copies (one per wave)
#define BASEK 0xBE4CCCCDu   // bits of 0.2f with sign-flag set (keys are score-bits | 0x80000000)
#define CANDMAX 256

// out layout: boxes_yxyx @0 ; in_zone @38400 ; scores @48000 ; classes @57600 ;
//             centers_yx @67200 ; keep @86400 ; total 96000 floats
#define O1 38400
#define O2 48000
#define O3 57600
#define O4 67200
#define O5 86400

// ws: keys @0 (32*8400*4 B). per-batch region @ 2 MiB + b*8192:
//   sel (300 ull) @+0 ; boxes planes x1,y1,x2,y2 (4*300 f32) @+2400 B
#define WS_BATCH_BASE (2u << 20)
#define WS_BATCH_STRIDE 8192

// ---------------- A: per-anchor score key (memory-bound, unchanged) ----------------
__global__ __launch_bounds__(256) void score_kernel(const float* __restrict__ pred,
                                                    uint32_t* __restrict__ keys) {
    __shared__ float sP[128 * 85];
    const int blk = blockIdx.x;                       // 2100 blocks * 128 anchors
    const float4* g4 = (const float4*)(pred + (size_t)blk * 128 * 85);
    float4* l4 = (float4*)sP;
    for (int i = threadIdx.x; i < (128 * 85 / 4); i += 256) l4[i] = g4[i];
    __syncthreads();
    const int t = threadIdx.x;
    if (t < 128) {
        const float* p = sP + t * 85;
        float obj = p[4];
        float b0 = p[5], b1 = p[6], b2 = p[7], b3 = p[8];
        #pragma unroll
        for (int c = 4; c < NC; c += 4) {
            b0 = fmaxf(b0, p[5 + c]);
            b1 = fmaxf(b1, p[6 + c]);
            b2 = fmaxf(b2, p[7 + c]);
            b3 = fmaxf(b3, p[8 + c]);
        }
        float best = fmaxf(fmaxf(b0, b1), fmaxf(b2, b3));
        float sc = obj * best;
        uint32_t u = (sc >= 0.2f) ? (__float_as_uint(sc) | 0x80000000u) : 0x007FFFFFu;
        keys[(size_t)blk * 128 + t] = u;
    }
}

__device__ __forceinline__ uint32_t key_bin(uint32_t k) {
    return (k < BASEK) ? 0u : (1u + ((k - BASEK) >> 16));   // max 308 < NBIN
}

// ---------------- B: dense-histogram select + rank sort + gather/outputs ----------------
__global__ __launch_bounds__(TB) void select_kernel(const float* __restrict__ pred,
                                                    const uint32_t* __restrict__ keys,
                                                    uint8_t* __restrict__ ws,
                                                    float* __restrict__ out) {
    #pragma clang fp contract(off)
    __shared__ uint32_t sKeys[NKPAD];
    __shared__ uint32_t sH[NCPY * HSTR];
    __shared__ ull sSel[KTOP];
    __shared__ ull sSorted[KTOP];
    __shared__ ull sCand[CANDMAX];
    __shared__ uint32_t sWTot[8];
    __shared__ uint32_t sBc[2];
    __shared__ uint32_t sRank[KTOP];
    __shared__ uint32_t sCN;

    const int b = blockIdx.x;
    const int t = threadIdx.x;
    const int lane = t & 63;
    const int wv = t >> 6;              // 0..7

    {   // coalesced key load (batch base 16B-aligned: 33600 % 16 == 0)
        const uint4* g4 = (const uint4*)(keys + (size_t)b * NA);
        uint4* l4 = (uint4*)sKeys;
        for (int i = t; i < NA / 4; i += TB) l4[i] = g4[i];
        for (int i = NA + t; i < NKPAD; i += TB) sKeys[i] = 0u;  // pads -> bin 0, never selected
    }
    for (int i = t; i < NCPY * HSTR; i += TB) sH[i] = 0u;
    if (t < KTOP) sRank[t] = 0u;
    __syncthreads();

    const int beg = t * CH;
    {   // ---- one-shot dense histogram (8 copies, one per wave) ----
        uint32_t* hw = &sH[wv * HSTR];
        #pragma unroll
        for (int e = 0; e < CH; ++e) {
            uint32_t k = sKeys[beg + e];
            atomicAdd(&hw[key_bin(k)], 1u);
        }
    }
    __syncthreads();

    // ---- suffix scan over 309 bins (waves 0..4), find threshold bin ----
    uint32_t v = 0, s = 0;
    if (t < 320) {
        if (t < NBIN) {
            #pragma unroll
            for (int c = 0; c < NCPY; ++c) v += sH[c * HSTR + t];
        }
        s = v;
        #pragma unroll
        for (int off = 1; off < 64; off <<= 1) {
            uint32_t o = __shfl_down(s, off, 64);
            if (lane + off < 64) s += o;
        }
        if (lane == 0) sWTot[wv] = s;
    }
    __syncthreads();
    if (t < 320) {
        uint32_t S = s;
        for (int w2 = wv + 1; w2 < 5; ++w2) S += sWTot[w2];
        uint32_t above = S - v;              // count of keys in bins strictly above t
        if (above < KTOP && S >= KTOP) {     // unique crossing bin
            sBc[0] = (uint32_t)t;
            sBc[1] = KTOP - above;
        }
    }
    __syncthreads();
    const uint32_t Tbin = sBc[0];
    const uint32_t rem = sBc[1];             // how many to take from bin Tbin
    const uint32_t cntgt = KTOP - rem;

    // ---- compact: bins>T -> sSel (unordered); bin==T -> candidates ----
    {
        uint32_t gtc = 0, eqc = 0;
        #pragma unroll
        for (int e = 0; e < CH; ++e) {
            uint32_t bin = key_bin(sKeys[beg + e]);
            gtc += (bin > Tbin) ? 1u : 0u;
            eqc += (bin == Tbin) ? 1u : 0u;
        }
        uint32_t pack = (gtc << 16) | eqc;   // gt total <= 300, eq total <= 8400: no overflow
        uint32_t ps = pack;
        #pragma unroll
        for (int off = 1; off < 64; off <<= 1) {
            uint32_t o = __shfl_up(ps, off, 64);
            if (lane >= off) ps += o;
        }
        if (lane == 63) sWTot[wv] = ps;
        __syncthreads();
        uint32_t excl = ps - pack;           // exclusive within wave
        #pragma unroll
        for (int w2 = 0; w2 < 8; ++w2) if (w2 < wv) excl += sWTot[w2];
        uint32_t gtoff = excl >> 16;
        uint32_t eqoff = excl & 0xFFFFu;
        if (t == TB - 1) {
            uint32_t tot = eqoff + eqc;
            sCN = (tot > CANDMAX) ? CANDMAX : tot;
        }
        #pragma unroll
        for (int e = 0; e < CH; ++e) {
            uint32_t k = sKeys[beg + e];
            uint32_t bin = key_bin(k);
            uint32_t idx = (uint32_t)(beg + e);
            if (bin > Tbin) {
                sSel[gtoff++] = ((ull)k << 32) | (ull)(0xFFFFFFFFu - idx);
            } else if (bin == Tbin) {
                if (eqoff < CANDMAX)
                    sCand[eqoff] = ((ull)k << 32) | (ull)(0xFFFFFFFFu - idx);
                eqoff++;
            }
        }
        __syncthreads();
    }

    // ---- candidate mini-rank: exact (key desc, idx asc) order; take top rem ----
    {
        int cn = (int)sCN;                   // expected ~30
        if (t < cn) {
            ull my = sCand[t];
            uint32_t rk = 0;
            for (int j = 0; j < cn; ++j) rk += (sCand[j] > my) ? 1u : 0u;
            if (rk < rem) sSel[cntgt + rk] = my;
        }
        __syncthreads();
    }

    // ---- rank sort over 1200 work items (unique 64-bit keys -> rank is a permutation) ----
    for (int p2 = t; p2 < KTOP * 4; p2 += TB) {
        const int i = p2 >> 2;
        const int q = p2 & 3;
        const ull my = sSel[i];
        const int j0 = q * 75, j1 = j0 + 75;
        uint32_t cnt = 0;
        for (int j = j0; j < j1; ++j)
            cnt += (sSel[j] > my) ? 1u : 0u;
        if (cnt) atomicAdd(&sRank[i], cnt);
    }
    __syncthreads();
    if (t < KTOP) sSorted[sRank[t]] = sSel[t];
    __syncthreads();

    // ---- fused gather: 2 threads/row, 4 first-max streams, exact first-max ----
    ull* selW = (ull*)(ws + WS_BATCH_BASE + (size_t)b * WS_BATCH_STRIDE);
    float* boxW = (float*)(selW + KTOP);
    const size_t bo = (size_t)b * KTOP;
    if (t < KTOP) selW[t] = sSorted[t];
    for (int tt = t; tt < 2 * KTOP; tt += TB) {       // pairs (2k,2k+1) share a wave & iteration
        const int row = tt >> 1;
        const int half = tt & 1;
        const uint32_t a = 0xFFFFFFFFu - (uint32_t)sSorted[row];
        const float* p = pred + ((size_t)b * NA + a) * 85;
        const int cbase = half * 40;
        float v0 = p[5 + cbase], v1 = p[6 + cbase], v2 = p[7 + cbase], v3 = p[8 + cbase];
        int   c0 = cbase, c1 = cbase + 1, c2 = cbase + 2, c3 = cbase + 3;
        #pragma unroll
        for (int c = 4; c < 40; c += 4) {
            float w0 = p[5 + cbase + c],     w1 = p[6 + cbase + c];
            float w2 = p[7 + cbase + c],     w3 = p[8 + cbase + c];
            if (w0 > v0) { v0 = w0; c0 = cbase + c; }        // strict >: first-in-stream
            if (w1 > v1) { v1 = w1; c1 = cbase + c + 1; }
            if (w2 > v2) { v2 = w2; c2 = cbase + c + 2; }
            if (w3 > v3) { v3 = w3; c3 = cbase + c + 3; }
        }
        float bv = v0; int bc = c0;
        if (v1 > bv || (v1 == bv && c1 < bc)) { bv = v1; bc = c1; }
        if (v2 > bv || (v2 == bv && c2 < bc)) { bv = v2; bc = c2; }
        if (v3 > bv || (v3 == bv && c3 < bc)) { bv = v3; bc = c3; }
        float pv = __shfl_xor(bv, 1, 64);
        int   pc = __shfl_xor(bc, 1, 64);
        if (half == 0) {
            if (pv > bv) { bv = pv; bc = pc; }   // partner indices larger: tie keeps ours
            float x = p[0], y = p[1], w = p[2], h = p[3], obj = p[4];
            float hw = w * 0.5f, hh = h * 0.5f;
            float x1 = x - hw, y1 = y - hh, x2 = x + hw, y2 = y + hh;
            boxW[row] = x1; boxW[KTOP + row] = y1;
            boxW[2 * KTOP + row] = x2; boxW[3 * KTOP + row] = y2;
            out[(bo + row) * 4 + 0] = y1;
            out[(bo + row) * 4 + 1] = x1;
            out[(bo + row) * 4 + 2] = y2;
            out[(bo + row) * 4 + 3] = x2;
            out[O4 + (bo + row) * 2 + 0] = (y1 + y2) * 0.5f;
            out[O4 + (bo + row) * 2 + 1] = (x1 + x2) * 0.5f;
            out[O2 + bo + row] = fmaxf(obj, bv);
            out[O3 + bo + row] = (float)bc;
        }
    }
}

// ---------------- C: IoU masks (zero-skip) + NMS + zone parity + final writes ----------------
__global__ __launch_bounds__(TB) void nms_kernel(const float* __restrict__ zone,
                                                 const uint8_t* __restrict__ ws,
                                                 float* __restrict__ out) {
    #pragma clang fp contract(off)
    __shared__ float sB0[KTOP], sB1[KTOP], sB2[KTOP], sB3[KTOP];
    __shared__ ull sMask[KTOP * 5];
    __shared__ ull sSel[KTOP];
    __shared__ uint32_t sPar[KTOP];
    __shared__ ull sKeepF[5];
    __shared__ float sZone[16];
    const int b = blockIdx.x;
    const int t = threadIdx.x;
    const int lane = t & 63;
    const int wv = t >> 6;
    const ull* selG = (const ull*)(ws + WS_BATCH_BASE + (size_t)b * WS_BATCH_STRIDE);
    const float* boxG = (const float*)(selG + KTOP);
    if (t < KTOP) {
        sSel[t] = selG[t];
        sB0[t] = boxG[t];            sB1[t] = boxG[KTOP + t];
        sB2[t] = boxG[2 * KTOP + t]; sB3[t] = boxG[3 * KTOP + t];
    }
    if (t < 16) sZone[t] = zone[t];
    __syncthreads();

    // ---- IoU masks, role-major; skip role blocks entirely below the diagonal ----
    for (int p2 = t; p2 < KTOP * 5; p2 += TB) {
        const int role = p2 / KTOP;
        const int i = p2 - role * KTOP;
        const int j0 = role * 64;
        int jmax = j0 + 64; if (jmax > KTOP) jmax = KTOP;
        if (jmax <= i + 1) { sMask[i * 5 + role] = 0ull; continue; }   // all j <= i: zero word
        float x1 = sB0[i], y1 = sB1[i], x2 = sB2[i], y2 = sB3[i];
        float ai = fmaxf(x2 - x1, 0.0f) * fmaxf(y2 - y1, 0.0f);
        ull bits = 0ull;
        for (int j = j0; j < jmax; ++j) {
            float bx1 = sB0[j], by1 = sB1[j], bx2 = sB2[j], by2 = sB3[j];
            float aj = fmaxf(bx2 - bx1, 0.0f) * fmaxf(by2 - by1, 0.0f);
            float iw = fminf(x2, bx2) - fmaxf(x1, bx1); iw = fmaxf(iw, 0.0f);
            float ih = fminf(y2, by2) - fmaxf(y1, by1); ih = fmaxf(ih, 0.0f);
            float inter = iw * ih;
            float den = ai + aj;             // mirror reference op order exactly
            den = den - inter;
            den = den + 1e-9f;
            float iou = inter / den;
            if (j > i && iou > 0.45f) bits |= (1ull << (j - j0));
        }
        sMask[i * 5 + role] = bits;
    }
    __syncthreads();

    // ---- wave 0: greedy NMS.  waves 1-5 (independent): zone parity ----
    const size_t bo = (size_t)b * KTOP;
    if (wv == 0) {
        ull rm[5][5];
        ull kw[5];
        #pragma unroll
        for (int w = 0; w < 5; ++w) {
            int i = w * 64 + lane;
            bool f = (i < KTOP) && (((uint32_t)(sSel[i] >> 32)) > 0x007FFFFFu);
            kw[w] = __ballot(f);             // keep-init, replicated in every lane
            #pragma unroll
            for (int ww = 0; ww < 5; ++ww)
                rm[w][ww] = (i < KTOP) ? sMask[i * 5 + ww] : 0ull;
        }
        #pragma unroll
        for (int w = 0; w < 5; ++w) {
            ull cur = kw[w];
            while (cur) {
                int ib = __builtin_ctzll(cur);          // accepted box i = w*64+ib
                ull m0 = __shfl(rm[w][0], ib);
                ull m1 = __shfl(rm[w][1], ib);
                ull m2 = __shfl(rm[w][2], ib);
                ull m3 = __shfl(rm[w][3], ib);
                ull m4 = __shfl(rm[w][4], ib);
                kw[0] &= ~m0; kw[1] &= ~m1; kw[2] &= ~m2; kw[3] &= ~m3; kw[4] &= ~m4;
                ull done = (ib == 63) ? 0ull : (~0ull << (ib + 1));
                cur = kw[w] & done;
            }
        }
        if (lane == 0) {
            #pragma unroll
            for (int w = 0; w < 5; ++w) sKeepF[w] = kw[w];
        }
    } else if (t >= 64 && t < 64 + KTOP) {
        const int i = t - 64;
        float cy = (sB1[i] + sB3[i]) * 0.5f;   // bit-identical to stored centers
        float cx = (sB0[i] + sB2[i]) * 0.5f;
        int cnt = 0;
        #pragma unroll
        for (int e = 0; e < 8; ++e) {
            float xi = sZone[2 * e], yi = sZone[2 * e + 1];
            int ep = (e + 7) & 7;               // zr = roll(zone, 1)
            float xj = sZone[2 * ep], yj = sZone[2 * ep + 1];
            bool gyi = yi > cy, gyj = yj > cy;
            if (gyi != gyj) {
                float gx = (xj - xi) * (cy - yi) / (yj - yi) + xi;
                if (gx > cx) cnt++;
            }
        }
        sPar[i] = (uint32_t)(cnt & 1);
    }
    __syncthreads();

    if (t < KTOP) {
        int kp = (int)((sKeepF[t >> 6] >> (t & 63)) & 1ull);
        int inz = (sPar[t] && kp) ? 1 : 0;
        out[O1 + bo + t] = (float)inz;
        out[O5 + bo + t] = (float)kp;
    }
}

extern "C" void kernel_launch(void* const* d_in, const int* in_sizes, int n_in,
                              void* d_out, int out_size, void* d_ws, size_t ws_size,
                              hipStream_t stream) {
    const float* pred = (const float*)d_in[0];   // (32,8400,85) fp32
    const float* zone = (const float*)d_in[1];   // (8,2) fp32
    float* out = (float*)d_out;                  // 96000 fp32
    uint32_t* keys = (uint32_t*)d_ws;            // keys @0 ; per-batch sel/boxes @2MiB
    uint8_t* ws = (uint8_t*)d_ws;

    score_kernel<<<(NB * NA) / 128, 256, 0, stream>>>(pred, keys);
    select_kernel<<<NB, TB, 0, stream>>>(pred, keys, ws, out);
    nms_kernel<<<NB, TB, 0, stream>>>(zone, ws, out);
}

// Round 7
// 185.692 us; speedup vs baseline: 1.1261x; 1.0424x over previous
//
#include <hip/hip_runtime.h>
#include <stdint.h>

typedef unsigned long long ull;

#define NA 8400
#define NB 32
#define KTOP 300
#define NC 80
#define TB 512         // 8 waves: VGPR budget 256, no spills (R5->R6 lesson)
#define CH 17          // 512*17 = 8704 >= 8400; keys live in registers
#define NBIN 309       // 1 underflow bin + (0xBF800000-0xBE4CCCCD)>>16 = 307 -> bins 1..308
#define HSTR 311       // odd stride: copies of one bin staggered across banks
#define NCPY 8         // histogram copies (one per wave)
#define BASEK 0xBE4CCCCDu   // bits of 0.2f with sign-flag set (keys are score-bits | 0x80000000)
#define CANDMAX 512

// out layout: boxes_yxyx @0 ; in_zone @38400 ; scores @48000 ; classes @57600 ;
//             centers_yx @67200 ; keep @86400 ; total 96000 floats
#define O1 38400
#define O2 48000
#define O3 57600
#define O4 67200
#define O5 86400

// ---------------- A: per-anchor score key (memory-bound, unchanged) ----------------
__global__ __launch_bounds__(256) void score_kernel(const float* __restrict__ pred,
                                                    uint32_t* __restrict__ keys) {
    __shared__ float sP[128 * 85];
    const int blk = blockIdx.x;                       // 2100 blocks * 128 anchors
    const float4* g4 = (const float4*)(pred + (size_t)blk * 128 * 85);
    float4* l4 = (float4*)sP;
    for (int i = threadIdx.x; i < (128 * 85 / 4); i += 256) l4[i] = g4[i];
    __syncthreads();
    const int t = threadIdx.x;
    if (t < 128) {
        const float* p = sP + t * 85;
        float obj = p[4];
        float b0 = p[5], b1 = p[6], b2 = p[7], b3 = p[8];
        #pragma unroll
        for (int c = 4; c < NC; c += 4) {
            b0 = fmaxf(b0, p[5 + c]);
            b1 = fmaxf(b1, p[6 + c]);
            b2 = fmaxf(b2, p[7 + c]);
            b3 = fmaxf(b3, p[8 + c]);
        }
        float best = fmaxf(fmaxf(b0, b1), fmaxf(b2, b3));
        float sc = obj * best;
        uint32_t u = (sc >= 0.2f) ? (__float_as_uint(sc) | 0x80000000u) : 0x007FFFFFu;
        keys[(size_t)blk * 128 + t] = u;
    }
}

__device__ __forceinline__ uint32_t key_bin(uint32_t k) {
    return (k < BASEK) ? 0u : (1u + ((k - BASEK) >> 16));   // max 308 < NBIN
}

// ---------------- B: one block per batch: select + sort + gather + IoU + NMS ----------------
// Enumeration order is irrelevant everywhere: gt-region order is fixed by the later exact
// 64-bit rank; threshold-bin order by the exact mini-rank. So keys load coalesced
// (idx = e*TB + t) straight into registers; no LDS key staging at all.
__global__ __launch_bounds__(TB) void batch_kernel(const float* __restrict__ pred,
                                                   const float* __restrict__ zone,
                                                   const uint32_t* __restrict__ keys,
                                                   float* __restrict__ out) {
    #pragma clang fp contract(off)
    __shared__ uint32_t sH[NCPY * HSTR];
    __shared__ ull sSel[KTOP];
    __shared__ ull sSorted[KTOP];
    __shared__ ull sCand[CANDMAX];
    __shared__ float sB0[KTOP], sB1[KTOP], sB2[KTOP], sB3[KTOP];
    __shared__ ull sMask[KTOP * 5];
    __shared__ uint32_t sWTot[8];
    __shared__ uint32_t sBc[2];
    __shared__ uint32_t sPar[KTOP];
    __shared__ ull sKeepF[5];
    __shared__ float sZone[16];
    __shared__ uint32_t sCN;

    const int b = blockIdx.x;
    const int t = threadIdx.x;
    const int lane = t & 63;
    const int wv = t >> 6;              // 0..7; also the histogram copy id

    // ---- coalesced key load into registers (pads -> key 0 -> bin 0, never selected) ----
    uint32_t myk[CH];
    #pragma unroll
    for (int e = 0; e < CH; ++e) {
        int idx = e * TB + t;
        myk[e] = (idx < NA) ? keys[(size_t)b * NA + idx] : 0u;
    }
    for (int i = t; i < NCPY * HSTR; i += TB) sH[i] = 0u;
    if (t < 16) sZone[t] = zone[t];
    __syncthreads();

    // ---- one-shot dense histogram (8 copies, one per wave) ----
    {
        uint32_t* hw = &sH[wv * HSTR];
        #pragma unroll
        for (int e = 0; e < CH; ++e)
            atomicAdd(&hw[key_bin(myk[e])], 1u);
    }
    __syncthreads();

    // ---- suffix scan over 309 bins (waves 0..4), find threshold bin ----
    uint32_t v = 0, s = 0;
    if (t < 320) {
        if (t < NBIN) {
            #pragma unroll
            for (int c = 0; c < NCPY; ++c) v += sH[c * HSTR + t];
        }
        s = v;
        #pragma unroll
        for (int off = 1; off < 64; off <<= 1) {
            uint32_t o = __shfl_down(s, off, 64);
            if (lane + off < 64) s += o;
        }
        if (lane == 0) sWTot[wv] = s;
    }
    __syncthreads();
    if (t < 320) {
        uint32_t S = s;
        for (int w2 = wv + 1; w2 < 5; ++w2) S += sWTot[w2];
        uint32_t above = S - v;              // keys in bins strictly above t
        if (above < KTOP && S >= KTOP) {     // unique crossing bin
            sBc[0] = (uint32_t)t;
            sBc[1] = KTOP - above;
        }
    }
    __syncthreads();
    const uint32_t Tbin = sBc[0];
    const uint32_t rem = sBc[1];             // how many to take from bin Tbin
    const uint32_t cntgt = KTOP - rem;

    // ---- compact: bins>T -> sSel[0..cntgt) (any order); bin==T -> sCand ----
    {
        uint32_t gtc = 0, eqc = 0;
        #pragma unroll
        for (int e = 0; e < CH; ++e) {
            uint32_t bin = key_bin(myk[e]);
            gtc += (bin > Tbin) ? 1u : 0u;
            eqc += (bin == Tbin) ? 1u : 0u;
        }
        uint32_t pack = (gtc << 16) | eqc;   // gt total <= 300, eq total <= 8400: no overflow
        uint32_t ps = pack;
        #pragma unroll
        for (int off = 1; off < 64; off <<= 1) {
            uint32_t o = __shfl_up(ps, off, 64);
            if (lane >= off) ps += o;
        }
        if (lane == 63) sWTot[wv] = ps;
        __syncthreads();
        uint32_t excl = ps - pack;           // exclusive within wave
        #pragma unroll
        for (int w2 = 0; w2 < 8; ++w2) if (w2 < wv) excl += sWTot[w2];
        uint32_t gtoff = excl >> 16;
        uint32_t eqoff = excl & 0xFFFFu;
        if (t == TB - 1) {
            uint32_t tot = eqoff + eqc;      // inclusive total of eq counts
            sCN = (tot > CANDMAX) ? CANDMAX : tot;
        }
        #pragma unroll
        for (int e = 0; e < CH; ++e) {
            uint32_t k = myk[e];
            uint32_t bin = key_bin(k);
            uint32_t idx = (uint32_t)(e * TB + t);
            if (bin > Tbin) {
                sSel[gtoff++] = ((ull)k << 32) | (ull)(0xFFFFFFFFu - idx);
            } else if (bin == Tbin) {
                if (eqoff < CANDMAX)
                    sCand[eqoff] = ((ull)k << 32) | (ull)(0xFFFFFFFFu - idx);
                eqoff++;
            }
        }
        __syncthreads();
    }

    // ---- candidate mini-rank: exact (key desc, idx asc); top rem fill sSel tail ----
    {
        int cn = (int)sCN;                   // expected ~27
        if (t < cn) {
            ull my = sCand[t];
            uint32_t rk = 0;
            for (int j = 0; j < cn; ++j) rk += (sCand[j] > my) ? 1u : 0u;
            if (rk < rem) sSel[cntgt + rk] = my;
        }
        __syncthreads();
    }

    // ---- fused gather + exact rank: 2 threads/row; global loads hide LDS rank chain ----
    // rank of sSel[i] over all 300 unique 64-bit keys == final sorted position.
    const size_t bo = (size_t)b * KTOP;
    for (int tt = t; tt < 2 * KTOP; tt += TB) {   // pairs (2k,2k+1) same wave & iteration
        const int row = tt >> 1;
        const int half = tt & 1;
        const ull selv = sSel[row];
        const uint32_t a = 0xFFFFFFFFu - (uint32_t)selv;
        const float* p = pred + ((size_t)b * NA + a) * 85;
        const int cbase = half * 40;
        float v0 = p[5 + cbase], v1 = p[6 + cbase], v2 = p[7 + cbase], v3 = p[8 + cbase];
        int   c0 = cbase, c1 = cbase + 1, c2 = cbase + 2, c3 = cbase + 3;
        #pragma unroll
        for (int c = 4; c < 40; c += 4) {
            float w0 = p[5 + cbase + c],     w1 = p[6 + cbase + c];
            float w2 = p[7 + cbase + c],     w3 = p[8 + cbase + c];
            if (w0 > v0) { v0 = w0; c0 = cbase + c; }        // strict >: first-in-stream
            if (w1 > v1) { v1 = w1; c1 = cbase + c + 1; }
            if (w2 > v2) { v2 = w2; c2 = cbase + c + 2; }
            if (w3 > v3) { v3 = w3; c3 = cbase + c + 3; }
        }
        // rank half: half 0 counts j=0..149, half 1 counts j=150..299 (2-addr broadcast)
        uint32_t rk = 0;
        const int jb = half * 150;
        for (int j = jb; j < jb + 150; ++j)
            rk += (sSel[j] > selv) ? 1u : 0u;
        // combine streams with index tie-break -> exact argmax-first
        float bv = v0; int bc = c0;
        if (v1 > bv || (v1 == bv && c1 < bc)) { bv = v1; bc = c1; }
        if (v2 > bv || (v2 == bv && c2 < bc)) { bv = v2; bc = c2; }
        if (v3 > bv || (v3 == bv && c3 < bc)) { bv = v3; bc = c3; }
        float pv = __shfl_xor(bv, 1, 64);
        int   pc = __shfl_xor(bc, 1, 64);
        uint32_t rko = __shfl_xor(rk, 1, 64);
        const uint32_t rank = rk + rko;
        if (half == 0) {
            if (pv > bv) { bv = pv; bc = pc; }   // partner indices larger: tie keeps ours
            float x = p[0], y = p[1], w = p[2], h = p[3], obj = p[4];
            float hw = w * 0.5f, hh = h * 0.5f;
            float x1 = x - hw, y1 = y - hh, x2 = x + hw, y2 = y + hh;
            sSorted[rank] = selv;
            sB0[rank] = x1; sB1[rank] = y1; sB2[rank] = x2; sB3[rank] = y2;
            out[(bo + rank) * 4 + 0] = y1;
            out[(bo + rank) * 4 + 1] = x1;
            out[(bo + rank) * 4 + 2] = y2;
            out[(bo + rank) * 4 + 3] = x2;
            out[O4 + (bo + rank) * 2 + 0] = (y1 + y2) * 0.5f;
            out[O4 + (bo + rank) * 2 + 1] = (x1 + x2) * 0.5f;
            out[O2 + bo + rank] = fmaxf(obj, bv);
            out[O3 + bo + rank] = (float)bc;
        }
    }
    __syncthreads();

    // ---- IoU masks, role-major; skip role blocks entirely below the diagonal ----
    for (int p2 = t; p2 < KTOP * 5; p2 += TB) {
        const int role = p2 / KTOP;
        const int i = p2 - role * KTOP;
        const int j0 = role * 64;
        int jmax = j0 + 64; if (jmax > KTOP) jmax = KTOP;
        if (jmax <= i + 1) { sMask[i * 5 + role] = 0ull; continue; }   // all j <= i: zero word
        float x1 = sB0[i], y1 = sB1[i], x2 = sB2[i], y2 = sB3[i];
        float ai = fmaxf(x2 - x1, 0.0f) * fmaxf(y2 - y1, 0.0f);
        ull bits = 0ull;
        for (int j = j0; j < jmax; ++j) {
            float bx1 = sB0[j], by1 = sB1[j], bx2 = sB2[j], by2 = sB3[j];
            float aj = fmaxf(bx2 - bx1, 0.0f) * fmaxf(by2 - by1, 0.0f);
            float iw = fminf(x2, bx2) - fmaxf(x1, bx1); iw = fmaxf(iw, 0.0f);
            float ih = fminf(y2, by2) - fmaxf(y1, by1); ih = fmaxf(ih, 0.0f);
            float inter = iw * ih;
            float den = ai + aj;             // mirror reference op order exactly
            den = den - inter;
            den = den + 1e-9f;
            float iou = inter / den;
            if (j > i && iou > 0.45f) bits |= (1ull << (j - j0));
        }
        sMask[i * 5 + role] = bits;
    }
    __syncthreads();

    // ---- wave 0: greedy NMS.  waves 1-5 (independent): zone parity ----
    if (wv == 0) {
        ull rm[5][5];
        ull kw[5];
        #pragma unroll
        for (int w = 0; w < 5; ++w) {
            int i = w * 64 + lane;
            bool f = (i < KTOP) && (((uint32_t)(sSorted[i] >> 32)) > 0x007FFFFFu);
            kw[w] = __ballot(f);             // keep-init, replicated in every lane
            #pragma unroll
            for (int ww = 0; ww < 5; ++ww)
                rm[w][ww] = (i < KTOP) ? sMask[i * 5 + ww] : 0ull;
        }
        #pragma unroll
        for (int w = 0; w < 5; ++w) {
            ull cur = kw[w];
            while (cur) {
                int ib = __builtin_ctzll(cur);          // accepted box i = w*64+ib
                ull m0 = __shfl(rm[w][0], ib);
                ull m1 = __shfl(rm[w][1], ib);
                ull m2 = __shfl(rm[w][2], ib);
                ull m3 = __shfl(rm[w][3], ib);
                ull m4 = __shfl(rm[w][4], ib);
                kw[0] &= ~m0; kw[1] &= ~m1; kw[2] &= ~m2; kw[3] &= ~m3; kw[4] &= ~m4;
                ull done = (ib == 63) ? 0ull : (~0ull << (ib + 1));
                cur = kw[w] & done;
            }
        }
        if (lane == 0) {
            #pragma unroll
            for (int w = 0; w < 5; ++w) sKeepF[w] = kw[w];
        }
    } else if (t >= 64 && t < 64 + KTOP) {
        const int i = t - 64;
        float cy = (sB1[i] + sB3[i]) * 0.5f;   // bit-identical to stored centers
        float cx = (sB0[i] + sB2[i]) * 0.5f;
        int cnt = 0;
        #pragma unroll
        for (int e = 0; e < 8; ++e) {
            float xi = sZone[2 * e], yi = sZone[2 * e + 1];
            int ep = (e + 7) & 7;               // zr = roll(zone, 1)
            float xj = sZone[2 * ep], yj = sZone[2 * ep + 1];
            bool gyi = yi > cy, gyj = yj > cy;
            if (gyi != gyj) {
                float gx = (xj - xi) * (cy - yi) / (yj - yi) + xi;
                if (gx > cx) cnt++;
            }
        }
        sPar[i] = (uint32_t)(cnt & 1);
    }
    __syncthreads();

    if (t < KTOP) {
        int kp = (int)((sKeepF[t >> 6] >> (t & 63)) & 1ull);
        int inz = (sPar[t] && kp) ? 1 : 0;
        out[O1 + bo + t] = (float)inz;
        out[O5 + bo + t] = (float)kp;
    }
}

extern "C" void kernel_launch(void* const* d_in, const int* in_sizes, int n_in,
                              void* d_out, int out_size, void* d_ws, size_t ws_size,
                              hipStream_t stream) {
    const float* pred = (const float*)d_in[0];   // (32,8400,85) fp32
    const float* zone = (const float*)d_in[1];   // (8,2) fp32
    float* out = (float*)d_out;                  // 96000 fp32
    uint32_t* keys = (uint32_t*)d_ws;            // 32*8400 u32 = 1.075 MB

    score_kernel<<<(NB * NA) / 128, 256, 0, stream>>>(pred, keys);
    batch_kernel<<<NB, TB, 0, stream>>>(pred, zone, keys, out);
}